// Round 1
// baseline (5728.284 us; speedup 1.0000x reference)
//
#include <hip/hip_runtime.h>
#include <math.h>

#define Bsz  1024
#define Tlen 128
#define Hdim 512
#define NCLS 10
#define NDIG 3
#define G4   2048   // 4*H

// ---- workspace layout (in floats) ----
#define W3_SZ   (Hdim * G4)       // 1,048,576  reordered Wh
#define GXD_SZ  (NDIG * G4)       // 6,144      per-digit input projections (+bias)
#define HB_SZ   (Bsz * Hdim)      // 524,288    one h buffer
#define W3_OFF  0
#define GXD_OFF (W3_OFF + W3_SZ)
#define H0_OFF  (GXD_OFF + GXD_SZ)
#define H1_OFF  (H0_OFF + HB_SZ)
#define C_OFF   (H1_OFF + HB_SZ)

// ---- prep: W3[jb][k][c] with c=(j'%32)*4+gate, j'=jb*32+(c>>2) ----
// Wh layout: (4H, H) row-major, rows stacked g,i,f,o.
__global__ __launch_bounds__(256) void prep_w3(const float* __restrict__ Wh,
                                               float* __restrict__ W3) {
    int idx = blockIdx.x * 256 + threadIdx.x;   // 1,048,576 total
    int c  = idx & 127;
    int k  = (idx >> 7) & 511;
    int jb = idx >> 16;
    int jp = jb * 32 + (c >> 2);
    int g  = c & 3;
    W3[idx] = Wh[(size_t)(g * Hdim + jp) * Hdim + k];
}

// ---- prep: gxd[d][jp*4+g] = emb[d]·Wx[row] + b[row], row = g*H+jp ----
__global__ __launch_bounds__(256) void prep_gxd(const float* __restrict__ emb,
                                                const float* __restrict__ Wx,
                                                const float* __restrict__ b,
                                                float* __restrict__ gxd) {
    int idx = blockIdx.x * 256 + threadIdx.x;
    if (idx >= NDIG * G4) return;
    int col = idx % G4;
    int d   = idx / G4;
    int jp  = col >> 2;
    int g   = col & 3;
    int row = g * Hdim + jp;
    gxd[idx] = emb[d * 2 + 0] * Wx[row * 2 + 0]
             + emb[d * 2 + 1] * Wx[row * 2 + 1]
             + b[row];
}

// ---- zero h0 / h1 / c (ws is poisoned 0xAA before every timed call) ----
__global__ __launch_bounds__(256) void zero_state(float* __restrict__ p, int n4) {
    int i = blockIdx.x * 256 + threadIdx.x;
    if (i < n4) ((float4*)p)[i] = make_float4(0.f, 0.f, 0.f, 0.f);
}

// ---- one LSTM timestep: z = gxd[x[b,t]] + h_prev·Whᵀ, gates, c/h update ----
// grid (16,16): blockIdx.x = batch tile (64 rows), blockIdx.y = jb (32 j' cols, all 4 gates)
#define BT 64
#define JT 32
#define KC 32
__global__ __launch_bounds__(256) void lstm_step(
    const float* __restrict__ h_prev, float* __restrict__ h_next,
    float* __restrict__ c_state, const float* __restrict__ W3,
    const float* __restrict__ gxd, const int* __restrict__ x, int t)
{
    __shared__ float h_s[KC][BT + 1];   // [k][b], padded
    __shared__ float w_s[KC * 128];     // [k][c], contiguous

    int b0  = blockIdx.x * BT;
    int jb  = blockIdx.y;
    int tid = threadIdx.x;
    int tb  = tid >> 4;   // 0..15 -> 4 batch rows each
    int tj  = tid & 15;   // 0..15 -> 2 j' each (8 cols with gates)

    float acc[32];
#pragma unroll
    for (int i = 0; i < 32; i++) acc[i] = 0.f;

    const float* wsrc = W3 + (size_t)jb * (Hdim * 128);

    for (int k0 = 0; k0 < Hdim; k0 += KC) {
        // stage h tile: 64b x 32k (2048 floats, 2 float4/thread)
#pragma unroll
        for (int u = 0; u < 2; u++) {
            int i  = tid + u * 256;
            int bb = i >> 3, kq = i & 7;
            float4 hv = *(const float4*)&h_prev[(size_t)(b0 + bb) * Hdim + k0 + kq * 4];
            h_s[kq * 4 + 0][bb] = hv.x;
            h_s[kq * 4 + 1][bb] = hv.y;
            h_s[kq * 4 + 2][bb] = hv.z;
            h_s[kq * 4 + 3][bb] = hv.w;
        }
        // stage W tile: 32k x 128c contiguous (4096 floats, 4 float4/thread)
        {
            const float4* src = (const float4*)(wsrc + (size_t)k0 * 128);
            float4* dst = (float4*)w_s;
#pragma unroll
            for (int u = 0; u < 4; u++) dst[tid + u * 256] = src[tid + u * 256];
        }
        __syncthreads();

        int tb4 = tb * 4, tj8 = tj * 8;
#pragma unroll
        for (int kk = 0; kk < KC; kk++) {
            float4 wa = *(float4*)&w_s[kk * 128 + tj8];
            float4 wb = *(float4*)&w_s[kk * 128 + tj8 + 4];
#pragma unroll
            for (int r = 0; r < 4; r++) {
                float hv = h_s[kk][tb4 + r];
                acc[r*8+0] += hv * wa.x; acc[r*8+1] += hv * wa.y;
                acc[r*8+2] += hv * wa.z; acc[r*8+3] += hv * wa.w;
                acc[r*8+4] += hv * wb.x; acc[r*8+5] += hv * wb.y;
                acc[r*8+6] += hv * wb.z; acc[r*8+7] += hv * wb.w;
            }
        }
        __syncthreads();
    }

    // epilogue: gates + state update for 4 b x 2 j'
    int jpA = jb * JT + tj * 2;
#pragma unroll
    for (int r = 0; r < 4; r++) {
        int b = b0 + tb * 4 + r;
        int d = x[b * Tlen + t];
        const float* gx = gxd + d * G4;
#pragma unroll
        for (int j2 = 0; j2 < 2; j2++) {
            int jp = jpA + j2;
            const float* g4 = gx + jp * 4;
            float* z = &acc[r * 8 + j2 * 4];
            float zg = z[0] + g4[0];
            float zi = z[1] + g4[1];
            float zf = z[2] + g4[2];
            float zo = z[3] + g4[3];
            float gv = tanhf(zg);
            float iv = 1.f / (1.f + __expf(-zi));
            float fv = 1.f / (1.f + __expf(-zf));
            float ov = 1.f / (1.f + __expf(-zo));
            size_t ci = (size_t)b * Hdim + jp;
            float cn = gv * iv + c_state[ci] * fv;
            c_state[ci] = cn;
            h_next[ci]  = tanhf(cn) * ov;
        }
    }
}

// ---- head: p = h·Wp + bp, log_softmax; one wave per batch row ----
__global__ __launch_bounds__(256) void head_kernel(
    const float* __restrict__ h, const float* __restrict__ Wp,
    const float* __restrict__ bp, float* __restrict__ out)
{
    __shared__ float wp_s[Hdim * NCLS];   // 20 KB
    int tid = threadIdx.x;
    for (int i = tid; i < Hdim * NCLS; i += 256) wp_s[i] = Wp[i];
    __syncthreads();

    int wave = tid >> 6, lane = tid & 63;
    int b = blockIdx.x * 4 + wave;

    float acc[NCLS];
#pragma unroll
    for (int c = 0; c < NCLS; c++) acc[c] = 0.f;
#pragma unroll
    for (int kk = 0; kk < Hdim / 64; kk++) {
        int k = kk * 64 + lane;
        float hv = h[(size_t)b * Hdim + k];
#pragma unroll
        for (int c = 0; c < NCLS; c++) acc[c] += hv * wp_s[k * NCLS + c];
    }
#pragma unroll
    for (int off = 32; off > 0; off >>= 1) {
#pragma unroll
        for (int c = 0; c < NCLS; c++) acc[c] += __shfl_down(acc[c], off);
    }
    if (lane == 0) {
        float p[NCLS], m = -1e30f;
#pragma unroll
        for (int c = 0; c < NCLS; c++) { p[c] = acc[c] + bp[c]; m = fmaxf(m, p[c]); }
        float s = 0.f;
#pragma unroll
        for (int c = 0; c < NCLS; c++) s += __expf(p[c] - m);
        float lse = m + logf(s);
#pragma unroll
        for (int c = 0; c < NCLS; c++) out[b * NCLS + c] = p[c] - lse;
    }
}

extern "C" void kernel_launch(void* const* d_in, const int* in_sizes, int n_in,
                              void* d_out, int out_size, void* d_ws, size_t ws_size,
                              hipStream_t stream) {
    const int*   x   = (const int*)d_in[0];
    const float* emb = (const float*)d_in[1];
    const float* Wx  = (const float*)d_in[2];
    const float* Wh  = (const float*)d_in[3];
    const float* b   = (const float*)d_in[4];
    const float* Wp  = (const float*)d_in[5];
    const float* bp  = (const float*)d_in[6];
    float* out = (float*)d_out;
    float* ws  = (float*)d_ws;

    float* W3  = ws + W3_OFF;
    float* gxd = ws + GXD_OFF;
    float* h0  = ws + H0_OFF;
    float* h1  = ws + H1_OFF;
    float* cst = ws + C_OFF;

    // prep (every call: ws is re-poisoned before each timed launch)
    prep_w3<<<W3_SZ / 256, 256, 0, stream>>>(Wh, W3);
    prep_gxd<<<(GXD_SZ + 255) / 256, 256, 0, stream>>>(emb, Wx, b, gxd);
    zero_state<<<(3 * HB_SZ / 4 + 255) / 256, 256, 0, stream>>>(h0, 3 * HB_SZ / 4);

    float* hp = h0;
    float* hn = h1;
    for (int t = 0; t < Tlen; t++) {
        lstm_step<<<dim3(Bsz / BT, Hdim / JT), 256, 0, stream>>>(
            hp, hn, cst, W3, gxd, x, t);
        float* tmp = hp; hp = hn; hn = tmp;
    }
    head_kernel<<<Bsz / 4, 256, 0, stream>>>(hp, Wp, bp, out);
}

// Round 2
// 1123.990 us; speedup vs baseline: 5.0964x; 5.0964x over previous
//
#include <hip/hip_runtime.h>
#include <math.h>

#define Bsz  1024
#define Tlen 128
#define Hdim 512
#define NCLS 10
#define NDIG 3
#define G4   2048   // 4*H

typedef short s8v  __attribute__((ext_vector_type(8)));   // 8 bf16 in 4 VGPRs
typedef float f16v __attribute__((ext_vector_type(16)));  // 32x32 mfma acc

// ---- workspace layout (bytes) ----
// W4 : 2 MB  bf16, fragment-order: [(nt*32+ks)*64 + lane] chunks of 8 bf16
// gxd: 24 KB fp32, [d][jp*4+g]
// h0 : 1 MB  bf16 [b][k]
// h1 : 1 MB  bf16
// c  : 2 MB  fp32 [b][jp]
#define W4_OFF  0
#define GXD_OFF (2*1024*1024)
#define H0_OFF  (GXD_OFF + 32*1024)
#define H1_OFF  (H0_OFF + 1024*1024)
#define C_OFF   (H1_OFF + 1024*1024)

static __device__ __forceinline__ unsigned short f2bf(float f) {
    unsigned int u = __float_as_uint(f);
    u = (u + 0x7FFFu + ((u >> 16) & 1u)) >> 16;   // RNE
    return (unsigned short)u;
}
static __device__ __forceinline__ float bf2f(unsigned short s) {
    return __uint_as_float(((unsigned int)s) << 16);
}
static __device__ __forceinline__ s8v u2s(uint4 v) {
    union { uint4 u; s8v s; } x; x.u = v; return x.s;
}

// ---- prep: W4 fragment chunks. n = nt*32+(l&31) -> jp=n>>2, g=n&3 -> Wh row g*512+jp
// element j of lane l in chunk (nt,ks): Wh[row][ks*16 + (l>>5)*8 + j], bf16 ----
__global__ __launch_bounds__(256) void prep_w4(const float* __restrict__ Wh,
                                               unsigned short* __restrict__ W4) {
    int idx = blockIdx.x * 256 + threadIdx.x;   // 0..131071
    int l  = idx & 63;
    int cs = idx >> 6;          // nt*32+ks
    int ks = cs & 31, nt = cs >> 5;
    int n  = nt * 32 + (l & 31);
    int jp = n >> 2, g = n & 3;
    int row = g * Hdim + jp;
    int kb  = ks * 16 + (l >> 5) * 8;
    const float* src = &Wh[(size_t)row * Hdim + kb];
    unsigned int p0 = f2bf(src[0]) | ((unsigned int)f2bf(src[1]) << 16);
    unsigned int p1 = f2bf(src[2]) | ((unsigned int)f2bf(src[3]) << 16);
    unsigned int p2 = f2bf(src[4]) | ((unsigned int)f2bf(src[5]) << 16);
    unsigned int p3 = f2bf(src[6]) | ((unsigned int)f2bf(src[7]) << 16);
    ((uint4*)W4)[idx] = make_uint4(p0, p1, p2, p3);
}

// ---- prep: gxd[d][jp*4+g] = emb[d]·Wx[row] + b[row], row = g*H+jp ----
__global__ __launch_bounds__(256) void prep_gxd(const float* __restrict__ emb,
                                                const float* __restrict__ Wx,
                                                const float* __restrict__ b,
                                                float* __restrict__ gxd) {
    int idx = blockIdx.x * 256 + threadIdx.x;
    if (idx >= NDIG * G4) return;
    int col = idx % G4;
    int d   = idx / G4;
    int jp  = col >> 2;
    int g   = col & 3;
    int row = g * Hdim + jp;
    gxd[idx] = emb[d * 2 + 0] * Wx[row * 2 + 0]
             + emb[d * 2 + 1] * Wx[row * 2 + 1]
             + b[row];
}

__global__ __launch_bounds__(256) void zero_state(float4* __restrict__ p, int n4) {
    int i = blockIdx.x * 256 + threadIdx.x;
    if (i < n4) p[i] = make_float4(0.f, 0.f, 0.f, 0.f);
}

// ---- one timestep: z = gxd[x[:,t]] + h_prev·Whᵀ  (bf16 MFMA), gates, c/h ----
// grid (16,16): x = batch tile (64 rows), y = jb (32 jp, gate-interleaved 128 n-cols)
// block 256 thr = 4 waves; wave w owns n-tile nt = jb*4+w (32 cols), both m-tiles.
__global__ __launch_bounds__(256) void lstm_step(
    const unsigned short* __restrict__ h_prev, unsigned short* __restrict__ h_next,
    float* __restrict__ c_state, const unsigned short* __restrict__ W4,
    const float* __restrict__ gxd, const int* __restrict__ x, int t)
{
    __shared__ uint4 h_s[4096];   // 64 KB: chunk ch = mt*32+ks, fragment-linear

    const int tid  = threadIdx.x;
    const int w    = tid >> 6;
    const int lane = tid & 63;
    const int b0   = blockIdx.x * 64;
    const int jb   = blockIdx.y;

    // ---- stage A tile (64 b-rows x 512 k, bf16) in fragment order ----
    {
        const int r  = lane & 31;
        const int hh = lane >> 5;
#pragma unroll
        for (int i = 0; i < 16; i++) {
            int ch = w * 16 + i;
            int mt = ch >> 5, ks = ch & 31;
            const uint4* src = (const uint4*)&h_prev[(size_t)(b0 + mt * 32 + r) * Hdim
                                                     + ks * 16 + hh * 8];
            h_s[ch * 64 + lane] = *src;
        }
    }
    __syncthreads();

    // ---- K loop: 32 ksubs of 16, no barriers ----
    f16v acc0 = {0,0,0,0,0,0,0,0,0,0,0,0,0,0,0,0};
    f16v acc1 = {0,0,0,0,0,0,0,0,0,0,0,0,0,0,0,0};
    const int nt = jb * 4 + w;
    const uint4* wp = (const uint4*)W4 + (size_t)nt * 32 * 64 + lane;
    const uint4* ap = &h_s[lane];
#pragma unroll
    for (int ks = 0; ks < 32; ks++) {
        s8v bf = u2s(wp[ks * 64]);
        s8v a0 = u2s(ap[ks * 64]);
        s8v a1 = u2s(ap[(32 + ks) * 64]);
        acc0 = __builtin_amdgcn_mfma_f32_32x32x16_bf16(a0, bf, acc0, 0, 0, 0);
        acc1 = __builtin_amdgcn_mfma_f32_32x32x16_bf16(a1, bf, acc1, 0, 0, 0);
    }
    __syncthreads();   // everyone done reading h_s

    // ---- z -> LDS (reuse h_s as float z_s[64][128]) ----
    float* z_s = (float*)h_s;
    {
        int col   = w * 32 + (lane & 31);
        int rbase = 4 * (lane >> 5);
#pragma unroll
        for (int reg = 0; reg < 16; reg++) {
            int row = (reg & 3) + 8 * (reg >> 2) + rbase;
            z_s[row * 128 + col]        = acc0[reg];
            z_s[(32 + row) * 128 + col] = acc1[reg];
        }
    }
    __syncthreads();

    // ---- fused gate epilogue: 8 (b,jp) per thread ----
    {
        int jpl  = tid & 31;
        int bg   = tid >> 5;          // 0..7
        int jcol = jb * 32 + jpl;
#pragma unroll
        for (int i = 0; i < 8; i++) {
            int bl = bg * 8 + i;
            int b  = b0 + bl;
            int d  = x[b * Tlen + t];
            float4 z4 = *(const float4*)&z_s[bl * 128 + jpl * 4];
            const float4 g4 = *(const float4*)&gxd[(size_t)d * G4 + jcol * 4];
            float zg = z4.x + g4.x, zi = z4.y + g4.y;
            float zf = z4.z + g4.z, zo = z4.w + g4.w;
            float gv = 1.f - 2.f / (__expf(2.f * zg) + 1.f);
            float iv = 1.f / (1.f + __expf(-zi));
            float fv = 1.f / (1.f + __expf(-zf));
            float ov = 1.f / (1.f + __expf(-zo));
            size_t ci = (size_t)b * Hdim + jcol;
            float cn = gv * iv + c_state[ci] * fv;
            c_state[ci] = cn;
            float hv = (1.f - 2.f / (__expf(2.f * cn) + 1.f)) * ov;
            h_next[ci] = f2bf(hv);
        }
    }
}

// ---- head: p = h·Wp + bp, log_softmax; one wave per batch row ----
__global__ __launch_bounds__(256) void head_kernel(
    const unsigned short* __restrict__ h, const float* __restrict__ Wp,
    const float* __restrict__ bp, float* __restrict__ out)
{
    __shared__ float wp_s[Hdim * NCLS];   // 20 KB
    int tid = threadIdx.x;
    for (int i = tid; i < Hdim * NCLS; i += 256) wp_s[i] = Wp[i];
    __syncthreads();

    int wave = tid >> 6, lane = tid & 63;
    int b = blockIdx.x * 4 + wave;

    float acc[NCLS];
#pragma unroll
    for (int c = 0; c < NCLS; c++) acc[c] = 0.f;
#pragma unroll
    for (int kk = 0; kk < Hdim / 64; kk++) {
        int k = kk * 64 + lane;
        float hv = bf2f(h[(size_t)b * Hdim + k]);
#pragma unroll
        for (int c = 0; c < NCLS; c++) acc[c] += hv * wp_s[k * NCLS + c];
    }
#pragma unroll
    for (int off = 32; off > 0; off >>= 1) {
#pragma unroll
        for (int c = 0; c < NCLS; c++) acc[c] += __shfl_down(acc[c], off);
    }
    if (lane == 0) {
        float p[NCLS], m = -1e30f;
#pragma unroll
        for (int c = 0; c < NCLS; c++) { p[c] = acc[c] + bp[c]; m = fmaxf(m, p[c]); }
        float s = 0.f;
#pragma unroll
        for (int c = 0; c < NCLS; c++) s += __expf(p[c] - m);
        float lse = m + logf(s);
#pragma unroll
        for (int c = 0; c < NCLS; c++) out[b * NCLS + c] = p[c] - lse;
    }
}

extern "C" void kernel_launch(void* const* d_in, const int* in_sizes, int n_in,
                              void* d_out, int out_size, void* d_ws, size_t ws_size,
                              hipStream_t stream) {
    const int*   x   = (const int*)d_in[0];
    const float* emb = (const float*)d_in[1];
    const float* Wx  = (const float*)d_in[2];
    const float* Wh  = (const float*)d_in[3];
    const float* b   = (const float*)d_in[4];
    const float* Wp  = (const float*)d_in[5];
    const float* bp  = (const float*)d_in[6];
    float* out = (float*)d_out;
    char*  ws  = (char*)d_ws;

    unsigned short* W4  = (unsigned short*)(ws + W4_OFF);
    float*          gxd = (float*)(ws + GXD_OFF);
    unsigned short* h0  = (unsigned short*)(ws + H0_OFF);
    unsigned short* h1  = (unsigned short*)(ws + H1_OFF);
    float*          cst = (float*)(ws + C_OFF);

    prep_w4<<<512, 256, 0, stream>>>(Wh, W4);
    prep_gxd<<<(NDIG * G4 + 255) / 256, 256, 0, stream>>>(emb, Wx, b, gxd);
    // zero h0 (1MB) + h1 (1MB) + c (2MB) contiguous
    zero_state<<<(4 * 1024 * 1024 / 16 + 255) / 256, 256, 0, stream>>>(
        (float4*)h0, 4 * 1024 * 1024 / 16);

    unsigned short* hp = h0;
    unsigned short* hn = h1;
    for (int t = 0; t < Tlen; t++) {
        lstm_step<<<dim3(Bsz / 64, G4 / 128), 256, 0, stream>>>(
            hp, hn, cst, W4, gxd, x, t);
        unsigned short* tmp = hp; hp = hn; hn = tmp;
    }
    head_kernel<<<Bsz / 4, 256, 0, stream>>>(hp, Wp, bp, out);
}

// Round 3
// 1071.434 us; speedup vs baseline: 5.3464x; 1.0491x over previous
//
#include <hip/hip_runtime.h>
#include <math.h>

#define Bsz  1024
#define Tlen 128
#define Hdim 512
#define NCLS 10
#define NDIG 3
#define G4   2048   // 4*H

typedef short s8v __attribute__((ext_vector_type(8)));   // 8 bf16 (4 VGPRs)
typedef float f4v __attribute__((ext_vector_type(4)));   // 16x16 mfma acc

// ---- workspace layout (bytes) ----
// W5 : 2 MB  bf16 fragment chunks: [((jg16*4 + g)*16 + ks)*64 + lane] x 16B
//      elem j of lane l = Wh[g*512 + jg16*16 + (l&15)][ks*32 + (l>>4)*8 + j]
// gxd: 24 KB fp32 [d][jp*4+g]
// h0/h1: 1 MB bf16 each, fragment-chunk layout per 64-row batch tile:
//      uint4 idx = bt*4096 + (msub*16+ks)*64 + lane;
//      elem j = h[bt*64 + msub*16 + (l&15)][ks*32 + (l>>4)*8 + j]
// c  : 2 MB fp32 [b][jp]
#define W5_OFF  0
#define GXD_OFF (2*1024*1024)
#define H0_OFF  (GXD_OFF + 32*1024)
#define H1_OFF  (H0_OFF + 1024*1024)
#define C_OFF   (H1_OFF + 1024*1024)

static __device__ __forceinline__ unsigned short f2bf(float f) {
    unsigned int u = __float_as_uint(f);
    u = (u + 0x7FFFu + ((u >> 16) & 1u)) >> 16;   // RNE
    return (unsigned short)u;
}
static __device__ __forceinline__ float bf2f(unsigned short s) {
    return __uint_as_float(((unsigned int)s) << 16);
}
static __device__ __forceinline__ s8v u2s(uint4 v) {
    union { uint4 u; s8v s; } x; x.u = v; return x.s;
}

// ---- prep: W5 fragment chunks (gate-major within each 16-jp group) ----
__global__ __launch_bounds__(256) void prep_w5(const float* __restrict__ Wh,
                                               unsigned short* __restrict__ W5) {
    int idx = blockIdx.x * 256 + threadIdx.x;   // 0..131071
    int l  = idx & 63;
    int c  = idx >> 6;
    int ks = c & 15;
    int g  = (c >> 4) & 3;
    int jg = c >> 6;                            // 0..31 (16-jp group)
    int row = g * Hdim + jg * 16 + (l & 15);
    int kb  = ks * 32 + (l >> 4) * 8;
    const float* src = &Wh[(size_t)row * Hdim + kb];
    unsigned int p0 = f2bf(src[0]) | ((unsigned int)f2bf(src[1]) << 16);
    unsigned int p1 = f2bf(src[2]) | ((unsigned int)f2bf(src[3]) << 16);
    unsigned int p2 = f2bf(src[4]) | ((unsigned int)f2bf(src[5]) << 16);
    unsigned int p3 = f2bf(src[6]) | ((unsigned int)f2bf(src[7]) << 16);
    ((uint4*)W5)[idx] = make_uint4(p0, p1, p2, p3);
}

// ---- prep: gxd[d][jp*4+g] = emb[d]·Wx[row] + b[row], row = g*H+jp ----
__global__ __launch_bounds__(256) void prep_gxd(const float* __restrict__ emb,
                                                const float* __restrict__ Wx,
                                                const float* __restrict__ b,
                                                float* __restrict__ gxd) {
    int idx = blockIdx.x * 256 + threadIdx.x;
    if (idx >= NDIG * G4) return;
    int col = idx % G4;
    int d   = idx / G4;
    int jp  = col >> 2;
    int g   = col & 3;
    int row = g * Hdim + jp;
    gxd[idx] = emb[d * 2 + 0] * Wx[row * 2 + 0]
             + emb[d * 2 + 1] * Wx[row * 2 + 1]
             + b[row];
}

__global__ __launch_bounds__(256) void zero_state(float4* __restrict__ p, int n4) {
    int i = blockIdx.x * 256 + threadIdx.x;
    if (i < n4) p[i] = make_float4(0.f, 0.f, 0.f, 0.f);
}

// ---- one timestep: barrier-free, LDS-free, gate-per-lane ----
// grid (16 bt, 16 jt), 512 thr = 8 waves: wave w -> msub = w&3 (16 b-rows),
// jps = w>>2 (16-jp half of the 32-jp tile). Wave computes m16 x jp16 x 4 gates.
__global__ __launch_bounds__(512, 2) void lstm_step(
    const uint4* __restrict__ h_prev, unsigned short* __restrict__ h_next,
    float* __restrict__ c_state, const uint4* __restrict__ W5,
    const float* __restrict__ gxd, const int* __restrict__ x, int t)
{
    const int tid  = threadIdx.x;
    const int w    = tid >> 6;
    const int lane = tid & 63;
    const int msub = w & 3;
    const int jps  = w >> 2;
    const int bt   = blockIdx.x;
    const int jt   = blockIdx.y;

    const uint4* ap = h_prev + bt * 4096 + msub * 16 * 64 + lane;
    const uint4* wq = W5 + (size_t)(jt * 2 + jps) * (4 * 16 * 64) + lane;

    f4v acc0 = {0.f, 0.f, 0.f, 0.f};
    f4v acc1 = {0.f, 0.f, 0.f, 0.f};
    f4v acc2 = {0.f, 0.f, 0.f, 0.f};
    f4v acc3 = {0.f, 0.f, 0.f, 0.f};

#pragma unroll
    for (int ks = 0; ks < 16; ks++) {
        s8v a  = u2s(ap[ks * 64]);
        s8v b0 = u2s(wq[(0 * 16 + ks) * 64]);
        s8v b1 = u2s(wq[(1 * 16 + ks) * 64]);
        s8v b2 = u2s(wq[(2 * 16 + ks) * 64]);
        s8v b3 = u2s(wq[(3 * 16 + ks) * 64]);
        acc0 = __builtin_amdgcn_mfma_f32_16x16x32_bf16(a, b0, acc0, 0, 0, 0);
        acc1 = __builtin_amdgcn_mfma_f32_16x16x32_bf16(a, b1, acc1, 0, 0, 0);
        acc2 = __builtin_amdgcn_mfma_f32_16x16x32_bf16(a, b2, acc2, 0, 0, 0);
        acc3 = __builtin_amdgcn_mfma_f32_16x16x32_bf16(a, b3, acc3, 0, 0, 0);
    }

    // epilogue straight out of accumulators: lane = (quad, col) has 4 b-rows x 1 jp
    const int quad = lane >> 4;
    const int col  = lane & 15;
    const int jcol = jt * 32 + jps * 16 + col;
    const int bbase = bt * 64 + msub * 16 + quad * 4;
    unsigned short* hn16 = h_next;
    const int chunk_base = bt * 4096 + (msub * 16 + (jcol >> 5)) * 64
                         + ((jcol >> 3) & 3) * 16;
    const int jlow = jcol & 7;

#pragma unroll
    for (int r = 0; r < 4; r++) {
        int b = bbase + r;
        int d = x[b * Tlen + t];
        const float4 g4 = *(const float4*)&gxd[(size_t)d * G4 + jcol * 4];
        float zg = acc0[r] + g4.x;
        float zi = acc1[r] + g4.y;
        float zf = acc2[r] + g4.z;
        float zo = acc3[r] + g4.w;
        float gv = 1.f - 2.f / (__expf(2.f * zg) + 1.f);
        float iv = 1.f / (1.f + __expf(-zi));
        float fv = 1.f / (1.f + __expf(-zf));
        float ov = 1.f / (1.f + __expf(-zo));
        size_t ci = (size_t)b * Hdim + jcol;
        float cn = gv * iv + c_state[ci] * fv;
        c_state[ci] = cn;
        float hv = (1.f - 2.f / (__expf(2.f * cn) + 1.f)) * ov;
        hn16[(size_t)(chunk_base + (b & 15)) * 8 + jlow] = f2bf(hv);
    }
}

// ---- head: p = h·Wp + bp, log_softmax; one wave per batch row ----
__global__ __launch_bounds__(256) void head_kernel(
    const uint4* __restrict__ h, const float* __restrict__ Wp,
    const float* __restrict__ bp, float* __restrict__ out)
{
    __shared__ float wp_s[Hdim * NCLS];   // 20 KB
    int tid = threadIdx.x;
    for (int i = tid; i < Hdim * NCLS; i += 256) wp_s[i] = Wp[i];
    __syncthreads();

    int wave = tid >> 6, lane = tid & 63;
    int b = blockIdx.x * 4 + wave;

    // lane l holds k = l*8 .. l*8+7 of row b (fragment-chunk gather)
    int uidx = (b >> 6) * 4096 + ((b >> 4) & 3) * 1024 + (lane >> 2) * 64
             + (lane & 3) * 16 + (b & 15);
    uint4 hv4 = h[uidx];
    union { uint4 u; unsigned short s[8]; } hu; hu.u = hv4;

    float acc[NCLS];
#pragma unroll
    for (int c = 0; c < NCLS; c++) acc[c] = 0.f;
#pragma unroll
    for (int j = 0; j < 8; j++) {
        int k = lane * 8 + j;
        float hvv = bf2f(hu.s[j]);
#pragma unroll
        for (int c = 0; c < NCLS; c++) acc[c] += hvv * wp_s[k * NCLS + c];
    }
#pragma unroll
    for (int off = 32; off > 0; off >>= 1) {
#pragma unroll
        for (int c = 0; c < NCLS; c++) acc[c] += __shfl_down(acc[c], off);
    }
    if (lane == 0) {
        float p[NCLS], m = -1e30f;
#pragma unroll
        for (int c = 0; c < NCLS; c++) { p[c] = acc[c] + bp[c]; m = fmaxf(m, p[c]); }
        float s = 0.f;
#pragma unroll
        for (int c = 0; c < NCLS; c++) s += __expf(p[c] - m);
        float lse = m + logf(s);
#pragma unroll
        for (int c = 0; c < NCLS; c++) out[b * NCLS + c] = p[c] - lse;
    }
}

extern "C" void kernel_launch(void* const* d_in, const int* in_sizes, int n_in,
                              void* d_out, int out_size, void* d_ws, size_t ws_size,
                              hipStream_t stream) {
    const int*   x   = (const int*)d_in[0];
    const float* emb = (const float*)d_in[1];
    const float* Wx  = (const float*)d_in[2];
    const float* Wh  = (const float*)d_in[3];
    const float* b   = (const float*)d_in[4];
    const float* Wp  = (const float*)d_in[5];
    const float* bp  = (const float*)d_in[6];
    float* out = (float*)d_out;
    char*  ws  = (char*)d_ws;

    unsigned short* W5  = (unsigned short*)(ws + W5_OFF);
    float*          gxd = (float*)(ws + GXD_OFF);
    unsigned short* h0  = (unsigned short*)(ws + H0_OFF);
    unsigned short* h1  = (unsigned short*)(ws + H1_OFF);
    float*          cst = (float*)(ws + C_OFF);

    prep_w5<<<512, 256, 0, stream>>>(Wh, W5);
    prep_gxd<<<(NDIG * G4 + 255) / 256, 256, 0, stream>>>(emb, Wx, b, gxd);
    // zero h0 + h1 + c (4 MB contiguous from H0_OFF)
    zero_state<<<(4 * 1024 * 1024 / 16 + 255) / 256, 256, 0, stream>>>(
        (float4*)h0, 4 * 1024 * 1024 / 16);

    unsigned short* hp = h0;
    unsigned short* hn = h1;
    for (int t = 0; t < Tlen; t++) {
        lstm_step<<<dim3(16, 16), 512, 0, stream>>>(
            (const uint4*)hp, hn, cst, (const uint4*)W5, gxd, x, t);
        unsigned short* tmp = hp; hp = hn; hn = tmp;
    }
    head_kernel<<<Bsz / 4, 256, 0, stream>>>((const uint4*)hp, Wp, bp, out);
}